// Round 1
// baseline (905.184 us; speedup 1.0000x reference)
//
#include <hip/hip_runtime.h>

#define N_NODES 8000
#define FDIM 256
#define NEG_SLOPE 0.2f

// ---------------- K1: H = X @ W^T + b  ----------------
// 16 rows per 256-thread block; X tile staged in LDS, thread f owns column f.
__global__ __launch_bounds__(256) void k_linear(const float* __restrict__ X,
                                                const float* __restrict__ W,
                                                const float* __restrict__ b,
                                                float* __restrict__ H) {
    __shared__ float Xs[16][260];               // pitch 260: 16B-aligned float4 rows
    const int t = threadIdx.x;
    const int i0 = blockIdx.x * 16;
    #pragma unroll
    for (int r = 0; r < 16; ++r)
        Xs[r][t] = X[(size_t)(i0 + r) * FDIM + t];   // coalesced, conflict-free store
    __syncthreads();
    const int f = t;
    float acc[16];
    const float bf = b[f];
    #pragma unroll
    for (int ii = 0; ii < 16; ++ii) acc[ii] = bf;
    for (int k4 = 0; k4 < FDIM / 4; ++k4) {
        const float4 w4 = *(const float4*)&W[(size_t)f * FDIM + k4 * 4];
        #pragma unroll
        for (int ii = 0; ii < 16; ++ii) {
            const float4 x4 = *(const float4*)&Xs[ii][k4 * 4];  // broadcast read
            acc[ii] += x4.x * w4.x + x4.y * w4.y + x4.z * w4.z + x4.w * w4.w;
        }
    }
    #pragma unroll
    for (int ii = 0; ii < 16; ++ii)
        H[(size_t)(i0 + ii) * FDIM + f] = acc[ii];
}

// ---------------- K2: hs = H@a_src + a_b, hd = H@a_dst ----------------
// one wave (64 lanes) per row; float4 loads + wave shuffle reduce.
__global__ __launch_bounds__(256) void k_attn_vec(const float* __restrict__ H,
                                                  const float* __restrict__ a_src,
                                                  const float* __restrict__ a_dst,
                                                  const float* __restrict__ a_b,
                                                  float* __restrict__ hs,
                                                  float* __restrict__ hd) {
    const int wave = threadIdx.x >> 6;
    const int lane = threadIdx.x & 63;
    const int i = blockIdx.x * 4 + wave;
    const float4 x = ((const float4*)H)[(size_t)i * 64 + lane];
    const float4 s = ((const float4*)a_src)[lane];
    const float4 d = ((const float4*)a_dst)[lane];
    float ps = x.x * s.x + x.y * s.y + x.z * s.z + x.w * s.w;
    float pd = x.x * d.x + x.y * d.y + x.z * d.z + x.w * d.w;
    #pragma unroll
    for (int off = 32; off; off >>= 1) {
        ps += __shfl_xor(ps, off);
        pd += __shfl_xor(pd, off);
    }
    if (lane == 0) { hs[i] = ps + *a_b; hd[i] = pd; }
}

// ---------------- K3: fused mask+leakyrelu+softmax+PV ----------------
// 16 output rows per 256-thread block. Single pass (no max subtraction:
// e = hs_i + hd_j + b is bounded ~|2|, exp cannot overflow in fp32).
// Per 64-j tile: weight phase -> w tile in LDS; PV phase -> each thread
// owns 2 columns (f, f+128) x 8 rows, float4 broadcast w reads.
__global__ __launch_bounds__(256) void k_gat(const float* __restrict__ H,
                                             const int* __restrict__ adj,
                                             const float* __restrict__ hs,
                                             const float* __restrict__ hd,
                                             float* __restrict__ out) {
    __shared__ float ws[64][20];   // pitch 20: float4-aligned, 8-way write conflict max
    __shared__ float hs_s[16];
    __shared__ float l_s[16];
    const int t = threadIdx.x;
    const int i0 = blockIdx.x * 16;
    if (t < 16) hs_s[t] = hs[i0 + t];
    __syncthreads();

    // weight-phase mapping: jj fast across lanes (coalesced adj)
    const int jj = t & 63;
    const int c  = t >> 6;        // wave id; ii = c + 4q
    // PV mapping: 2 columns x 8 rows per thread
    const int f  = t & 127;
    const int rg = t >> 7;

    float lpart[4] = {0.f, 0.f, 0.f, 0.f};
    float acc[8][2];
    #pragma unroll
    for (int m = 0; m < 8; ++m) { acc[m][0] = 0.f; acc[m][1] = 0.f; }

    for (int j0 = 0; j0 < N_NODES; j0 += 64) {
        // ---- weight phase ----
        const float hdv = hd[j0 + jj];
        #pragma unroll
        for (int q = 0; q < 4; ++q) {
            const int ii = c + 4 * q;
            const int a = adj[(size_t)(i0 + ii) * N_NODES + j0 + jj];
            float e = hs_s[ii] + hdv;
            e = (e >= 0.f) ? e : NEG_SLOPE * e;
            const float w = a ? __expf(e) : 0.f;
            lpart[q] += w;
            ws[jj][ii] = w;
        }
        __syncthreads();
        // ---- PV phase ----
        #pragma unroll 4
        for (int u = 0; u < 64; ++u) {
            const int j = j0 + u;
            const float h0 = H[(size_t)j * FDIM + f];
            const float h1 = H[(size_t)j * FDIM + f + 128];
            const float4 wa = *(const float4*)&ws[u][rg * 8];
            const float4 wb = *(const float4*)&ws[u][rg * 8 + 4];
            acc[0][0] += wa.x * h0; acc[0][1] += wa.x * h1;
            acc[1][0] += wa.y * h0; acc[1][1] += wa.y * h1;
            acc[2][0] += wa.z * h0; acc[2][1] += wa.z * h1;
            acc[3][0] += wa.w * h0; acc[3][1] += wa.w * h1;
            acc[4][0] += wb.x * h0; acc[4][1] += wb.x * h1;
            acc[5][0] += wb.y * h0; acc[5][1] += wb.y * h1;
            acc[6][0] += wb.z * h0; acc[6][1] += wb.z * h1;
            acc[7][0] += wb.w * h0; acc[7][1] += wb.w * h1;
        }
        __syncthreads();
    }

    // reduce row sums: each wave holds partials for ii = c + 4q
    #pragma unroll
    for (int q = 0; q < 4; ++q) {
        float v = lpart[q];
        #pragma unroll
        for (int off = 32; off; off >>= 1) v += __shfl_xor(v, off);
        if ((t & 63) == 0) l_s[c + 4 * q] = v;
    }
    __syncthreads();

    #pragma unroll
    for (int m = 0; m < 8; ++m) {
        const int ii = rg * 8 + m;
        const float linv = 1.0f / l_s[ii];
        out[(size_t)(i0 + ii) * FDIM + f]       = acc[m][0] * linv;
        out[(size_t)(i0 + ii) * FDIM + f + 128] = acc[m][1] * linv;
    }
}

extern "C" void kernel_launch(void* const* d_in, const int* in_sizes, int n_in,
                              void* d_out, int out_size, void* d_ws, size_t ws_size,
                              hipStream_t stream) {
    const float* X     = (const float*)d_in[0];
    const int*   adj   = (const int*)d_in[1];
    const float* Ww    = (const float*)d_in[2];
    const float* Wb    = (const float*)d_in[3];
    const float* a_src = (const float*)d_in[4];
    const float* a_dst = (const float*)d_in[5];
    const float* a_b   = (const float*)d_in[6];
    float* out = (float*)d_out;

    float* H  = (float*)d_ws;                       // 8000*256 f32 = 8.192 MB
    float* hs = H + (size_t)N_NODES * FDIM;         // 8000 f32
    float* hd = hs + N_NODES;                       // 8000 f32

    k_linear<<<N_NODES / 16, 256, 0, stream>>>(X, Ww, Wb, H);
    k_attn_vec<<<N_NODES / 4, 256, 0, stream>>>(H, a_src, a_dst, a_b, hs, hd);
    k_gat<<<N_NODES / 16, 256, 0, stream>>>(H, adj, hs, hd, out);
}

// Round 2
// 181.151 us; speedup vs baseline: 4.9969x; 4.9969x over previous
//
#include <hip/hip_runtime.h>

#define NN 8000
#define FD 256
#define NEG_SLOPE 0.2f
#define BM 32
#define KT 64
#define NSTEP (NN / KT)   // 125

typedef __bf16 bf16;
typedef __bf16 bf16x8 __attribute__((ext_vector_type(8)));
typedef __bf16 bf16x4 __attribute__((ext_vector_type(4)));
typedef float f32x4 __attribute__((ext_vector_type(4)));

// ---------------- K1: H = X @ W^T + b -> Ht (bf16, transposed [f][i]) ----------------
__global__ __launch_bounds__(256) void k_linear(const float* __restrict__ X,
                                                const float* __restrict__ W,
                                                const float* __restrict__ b,
                                                bf16* __restrict__ Ht) {
    __shared__ float Xs[16][260];
    const int t = threadIdx.x;
    const int i0 = blockIdx.x * 16;
    #pragma unroll
    for (int r = 0; r < 16; ++r)
        Xs[r][t] = X[(size_t)(i0 + r) * FD + t];
    __syncthreads();
    const int f = t;
    float acc[16];
    const float bf_ = b[f];
    #pragma unroll
    for (int ii = 0; ii < 16; ++ii) acc[ii] = bf_;
    for (int k4 = 0; k4 < FD / 4; ++k4) {
        const float4 w4 = *(const float4*)&W[(size_t)f * FD + k4 * 4];
        #pragma unroll
        for (int ii = 0; ii < 16; ++ii) {
            const float4 x4 = *(const float4*)&Xs[ii][k4 * 4];
            acc[ii] += x4.x * w4.x + x4.y * w4.y + x4.z * w4.z + x4.w * w4.w;
        }
    }
    bf16x8 v0, v1;
    #pragma unroll
    for (int ii = 0; ii < 8; ++ii) { v0[ii] = (bf16)acc[ii]; v1[ii] = (bf16)acc[ii + 8]; }
    *(bf16x8*)&Ht[(size_t)f * NN + i0]     = v0;   // 16B aligned: f*16000 + i0*2
    *(bf16x8*)&Ht[(size_t)f * NN + i0 + 8] = v1;
}

// ---------------- K2: hs = H@a_src + a_b, hd = H@a_dst (from Ht) ----------------
__global__ __launch_bounds__(256) void k_attn_vec(const bf16* __restrict__ Ht,
                                                  const float* __restrict__ a_src,
                                                  const float* __restrict__ a_dst,
                                                  const float* __restrict__ a_b,
                                                  float* __restrict__ hs,
                                                  float* __restrict__ hd) {
    __shared__ float psh[4][64], pdh[4][64];
    const int t = threadIdx.x;
    const int li = t & 63;
    const int q = t >> 6;
    const int i = blockIdx.x * 64 + li;
    float ps = 0.f, pd = 0.f;
    #pragma unroll 8
    for (int fi = 0; fi < 64; ++fi) {
        const int f = q * 64 + fi;
        const float h = (float)Ht[(size_t)f * NN + i];   // coalesced 128B/wave
        ps += h * a_src[f];
        pd += h * a_dst[f];
    }
    psh[q][li] = ps; pdh[q][li] = pd;
    __syncthreads();
    if (q == 0) {
        ps = psh[0][li] + psh[1][li] + psh[2][li] + psh[3][li];
        pd = pdh[0][li] + pdh[1][li] + pdh[2][li] + pdh[3][li];
        hs[i] = ps + a_b[0];
        hd[i] = pd;
    }
}

// ---------------- K3: fused weights + online-sum + MFMA PV ----------------
// 32 rows/block, 512 threads (8 waves = 2 row-strips x 4 col-groups).
// Per KT=64 j-tile: weight phase -> swizzled Wt (A operand); Ht tile staged
// via global_load_lds (pre-swizzled global src, linear LDS dest), double
// buffered with counted vmcnt. PV = mfma_f32_16x16x32_bf16.
__global__ __launch_bounds__(512) void k_gat(const bf16* __restrict__ Ht,
                                             const int* __restrict__ adj,
                                             const float* __restrict__ hs,
                                             const float* __restrict__ hd,
                                             float* __restrict__ out) {
    __shared__ __attribute__((aligned(16))) bf16 Bt[2][FD * KT];  // 2 x 32KB
    __shared__ __attribute__((aligned(16))) bf16 Wt[BM * KT];     // 4KB
    __shared__ float hd_s[NN];                                    // 32KB
    __shared__ float hs_s[BM];
    __shared__ float l_s[BM];

    const int t  = threadIdx.x;
    const int l  = t & 63;
    const int wv = t >> 6;
    const int i0 = blockIdx.x * BM;

    // weight-phase mapping
    const int ii = t >> 4;            // row 0..31 (16 threads per row)
    const int jm = (t & 15) * 4;      // 4 j's per thread
    const int slotW = (t & 15) >> 1;
    const int halfW = (t & 15) & 1;

    // MFMA mapping
    const int rs = wv >> 2;           // row strip 0..1
    const int cg = wv & 3;            // col group 0..3 (64 cols)
    const int al = l & 15;
    const int asl = l >> 4;
    const int ar = rs * 16 + al;      // A row
    const int arx = ar & 7;
    const int cswz = al & 7;          // (col&7) for all this lane's B cols

    // stage hd, hs into LDS
    {
        float4* hd4 = (float4*)hd_s;
        const float4* hdg = (const float4*)hd;
        for (int k = t; k < NN / 4; k += 512) hd4[k] = hdg[k];
        if (t < BM) hs_s[t] = hs[i0 + t];
    }

    // B-tile stage: LDS linear dest (wave-uniform base + lane*16),
    // global src pre-swizzled so read-side XOR swizzle sees the right data.
    auto stage = [&](int s_, int bufi) {
        const int j0 = s_ * KT;
        #pragma unroll
        for (int q = 0; q < 4; ++q) {
            const int idx16 = t + q * 512;
            const int col = idx16 >> 3;
            const int dslot = idx16 & 7;
            const int sslot = dslot ^ (col & 7);
            const bf16* src = Ht + (size_t)col * NN + j0 + sslot * 8;
            bf16* ldst = &Bt[bufi][(size_t)(wv * 64 + q * 512) * 8];
            __builtin_amdgcn_global_load_lds(
                (const __attribute__((address_space(1))) void*)src,
                (__attribute__((address_space(3))) void*)ldst, 16, 0, 0);
        }
    };

    const size_t adjbase = (size_t)(i0 + ii) * NN + jm;
    int4 adj_cur = *(const int4*)&adj[adjbase];
    stage(0, 0);
    __syncthreads();   // drains everything once (prologue only)

    const float hsv = hs_s[ii];
    float lsum = 0.f;
    f32x4 acc0 = {0.f, 0.f, 0.f, 0.f}, acc1 = acc0, acc2 = acc0, acc3 = acc0;

    #pragma unroll 1
    for (int s = 0; s < NSTEP; ++s) {
        const int buf = s & 1;
        int4 adj_nxt;
        if (s < NSTEP - 1) {
            adj_nxt = *(const int4*)&adj[adjbase + (size_t)(s + 1) * KT];
            stage(s + 1, buf ^ 1);
        }
        // ---- weight phase ----
        {
            const float4 hdv = *(const float4*)&hd_s[s * KT + jm];
            bf16x4 wv4;
            float e, w;
            e = hsv + hdv.x; e = e >= 0.f ? e : NEG_SLOPE * e; w = adj_cur.x ? __expf(e) : 0.f; lsum += w; wv4[0] = (bf16)w;
            e = hsv + hdv.y; e = e >= 0.f ? e : NEG_SLOPE * e; w = adj_cur.y ? __expf(e) : 0.f; lsum += w; wv4[1] = (bf16)w;
            e = hsv + hdv.z; e = e >= 0.f ? e : NEG_SLOPE * e; w = adj_cur.z ? __expf(e) : 0.f; lsum += w; wv4[2] = (bf16)w;
            e = hsv + hdv.w; e = e >= 0.f ? e : NEG_SLOPE * e; w = adj_cur.w ? __expf(e) : 0.f; lsum += w; wv4[3] = (bf16)w;
            *(bf16x4*)&Wt[ii * KT + ((slotW ^ (ii & 7)) * 8) + halfW * 4] = wv4;
        }
        if (s < NSTEP - 1) asm volatile("s_waitcnt vmcnt(5) lgkmcnt(0)" ::: "memory");
        else               asm volatile("s_waitcnt vmcnt(0) lgkmcnt(0)" ::: "memory");
        __builtin_amdgcn_s_barrier();
        __builtin_amdgcn_sched_barrier(0);

        // ---- MFMA phase ----
        {
            const bf16* Wrow = &Wt[ar * KT];
            const bf16x8 a0 = *(const bf16x8*)&Wrow[((0 + asl) ^ arx) * 8];
            const bf16x8 a1 = *(const bf16x8*)&Wrow[((4 + asl) ^ arx) * 8];
            const bf16* Bb = &Bt[buf][0];
            const int colb = cg * 64 + al;
            const bf16x8 b00 = *(const bf16x8*)&Bb[(colb +  0) * KT + ((0 + asl) ^ cswz) * 8];
            const bf16x8 b01 = *(const bf16x8*)&Bb[(colb +  0) * KT + ((4 + asl) ^ cswz) * 8];
            const bf16x8 b10 = *(const bf16x8*)&Bb[(colb + 16) * KT + ((0 + asl) ^ cswz) * 8];
            const bf16x8 b11 = *(const bf16x8*)&Bb[(colb + 16) * KT + ((4 + asl) ^ cswz) * 8];
            const bf16x8 b20 = *(const bf16x8*)&Bb[(colb + 32) * KT + ((0 + asl) ^ cswz) * 8];
            const bf16x8 b21 = *(const bf16x8*)&Bb[(colb + 32) * KT + ((4 + asl) ^ cswz) * 8];
            const bf16x8 b30 = *(const bf16x8*)&Bb[(colb + 48) * KT + ((0 + asl) ^ cswz) * 8];
            const bf16x8 b31 = *(const bf16x8*)&Bb[(colb + 48) * KT + ((4 + asl) ^ cswz) * 8];
            acc0 = __builtin_amdgcn_mfma_f32_16x16x32_bf16(a0, b00, acc0, 0, 0, 0);
            acc0 = __builtin_amdgcn_mfma_f32_16x16x32_bf16(a1, b01, acc0, 0, 0, 0);
            acc1 = __builtin_amdgcn_mfma_f32_16x16x32_bf16(a0, b10, acc1, 0, 0, 0);
            acc1 = __builtin_amdgcn_mfma_f32_16x16x32_bf16(a1, b11, acc1, 0, 0, 0);
            acc2 = __builtin_amdgcn_mfma_f32_16x16x32_bf16(a0, b20, acc2, 0, 0, 0);
            acc2 = __builtin_amdgcn_mfma_f32_16x16x32_bf16(a1, b21, acc2, 0, 0, 0);
            acc3 = __builtin_amdgcn_mfma_f32_16x16x32_bf16(a0, b30, acc3, 0, 0, 0);
            acc3 = __builtin_amdgcn_mfma_f32_16x16x32_bf16(a1, b31, acc3, 0, 0, 0);
        }
        asm volatile("s_waitcnt lgkmcnt(0)" ::: "memory");
        __builtin_amdgcn_s_barrier();
        __builtin_amdgcn_sched_barrier(0);

        adj_cur = adj_nxt;
    }

    // row-sum reduce (16 lanes per row)
    lsum += __shfl_xor(lsum, 1);
    lsum += __shfl_xor(lsum, 2);
    lsum += __shfl_xor(lsum, 4);
    lsum += __shfl_xor(lsum, 8);
    if ((l & 15) == 0) l_s[ii] = lsum;
    __syncthreads();

    // epilogue: D frag row = rs*16 + asl*4 + g, col = cg*64 + ct*16 + al
    const int r0 = rs * 16 + asl * 4;
    #pragma unroll
    for (int g = 0; g < 4; ++g) {
        const float rinv = 1.0f / l_s[r0 + g];
        float* orow = out + (size_t)(i0 + r0 + g) * FD + cg * 64 + al;
        orow[0]  = acc0[g] * rinv;
        orow[16] = acc1[g] * rinv;
        orow[32] = acc2[g] * rinv;
        orow[48] = acc3[g] * rinv;
    }
}

extern "C" void kernel_launch(void* const* d_in, const int* in_sizes, int n_in,
                              void* d_out, int out_size, void* d_ws, size_t ws_size,
                              hipStream_t stream) {
    const float* X     = (const float*)d_in[0];
    const int*   adj   = (const int*)d_in[1];
    const float* Ww    = (const float*)d_in[2];
    const float* Wb    = (const float*)d_in[3];
    const float* a_src = (const float*)d_in[4];
    const float* a_dst = (const float*)d_in[5];
    const float* a_b   = (const float*)d_in[6];
    float* out = (float*)d_out;

    bf16*  Ht = (bf16*)d_ws;                          // 256*8000*2 = 4.096 MB
    float* hs = (float*)((char*)d_ws + (size_t)FD * NN * sizeof(bf16));
    float* hd = hs + NN;

    k_linear<<<NN / 16, 256, 0, stream>>>(X, Ww, Wb, Ht);
    k_attn_vec<<<NN / 64, 256, 0, stream>>>(Ht, a_src, a_dst, a_b, hs, hd);
    k_gat<<<NN / BM, 512, 0, stream>>>(Ht, adj, hs, hd, out);
}